// Round 4
// baseline (471.260 us; speedup 1.0000x reference)
//
#include <hip/hip_runtime.h>
#include <hip/hip_bf16.h>

#define NTOK 4096
#define CDIM 256
#define HDIM 1024
#define NEXP 32
#define MT   128
#define LDX  264   // XH row stride in shorts
#define TP   72    // cvt LDS transpose pitch (shorts): 144B, 8B/16B aligned rows

typedef __bf16 bf16x8 __attribute__((ext_vector_type(8)));
typedef float  f32x4  __attribute__((ext_vector_type(4)));

__device__ __forceinline__ unsigned short f2bf(float f) {
    __hip_bfloat16 h = __float2bfloat16(f);
    return __builtin_bit_cast(unsigned short, h);
}

__device__ __forceinline__ float gelu_tanh(float v) {
    float c = 0.7978845608028654f * (v + 0.044715f * v * v * v);
    return 0.5f * v * (1.0f + tanhf(c));
}

// =============== mega kernel: router (+x->bf16, +out zeroing) | weight shuffle ===============
// blocks [0,1024): router for 4 tokens each + zero 4KB of out accum region
// blocks [1024,3072): weight convert/shuffle, 4 supertiles (32k x 64n) each via LDS transpose
__launch_bounds__(256, 4)
__global__ void k_prep(const float* __restrict__ x, const float* __restrict__ gW,
                       const float* __restrict__ gb, const float* __restrict__ eb,
                       const float* __restrict__ W1, const float* __restrict__ W2,
                       float* __restrict__ rw, unsigned short* __restrict__ xb,
                       int* __restrict__ cur, int* __restrict__ list, float* __restrict__ w4,
                       unsigned short* __restrict__ W1s, unsigned short* __restrict__ W2s,
                       float* __restrict__ outz)
{
    __shared__ __align__(16) unsigned char SMEM[4 * 32 * TP * 2];
    const int bx = blockIdx.x, tid = threadIdx.x;
    const int l = tid & 63, q = l >> 4, m16 = l & 15;

    if (bx < 1024) {
        // ---------- router part ----------
        // zero the out accumulation region: 1024 blocks x 256 threads x 16B = 4MB
        const f32x4 z4 = {0.f, 0.f, 0.f, 0.f};
        *(f32x4*)(outz + ((size_t)bx * 256 + tid) * 4) = z4;

        float* xs = (float*)SMEM;          // [4][256]
        const int wv = tid >> 6;
        const int n = bx * 4 + wv;
        const float* xr = x + (size_t)n * CDIM;
        float4 v = *(const float4*)(xr + l * 4);
        ushort4 u; u.x = f2bf(v.x); u.y = f2bf(v.y); u.z = f2bf(v.z); u.w = f2bf(v.w);
        *(ushort4*)(xb + (size_t)n * CDIM + l * 4) = u;
        *(float4*)(&xs[wv * 256 + l * 4]) = v;
        __syncthreads();

        float logit = -1e30f;
        if (l < 31) {
            float acc = 0.f;
            #pragma unroll 8
            for (int k = 0; k < CDIM; ++k) acc = fmaf(xs[wv * 256 + k], gW[k * 31 + l], acc);
            logit = acc + gb[l];
        }
        float mx = logit;
        #pragma unroll
        for (int o = 32; o; o >>= 1) mx = fmaxf(mx, __shfl_xor(mx, o));
        float p = (l < 31) ? expf(logit - mx) : 0.f;
        float s = p;
        #pragma unroll
        for (int o = 32; o; o >>= 1) s += __shfl_xor(s, o);
        float bv = (l < 31) ? p / s + eb[l] : -1e30f;
        float tv[3]; int ti[3];
        #pragma unroll
        for (int r = 0; r < 3; ++r) {
            float m = bv;
            #pragma unroll
            for (int o = 32; o; o >>= 1) m = fmaxf(m, __shfl_xor(m, o));
            unsigned long long msk = __ballot(bv == m);
            int src = __ffsll(msk) - 1;      // ties -> lowest index, matches lax.top_k
            tv[r] = m; ti[r] = src;
            if (l == src) bv = -1e30f;
        }
        float invs = 0.75f / (tv[0] + tv[1] + tv[2]);
        float w0 = tv[0] * invs, w1 = tv[1] * invs, w2 = tv[2] * invs;
        if (l < 32) {
            float val = (l == 0) ? 0.25f : 0.f;
            if (l == ti[0] + 1) val = w0;
            if (l == ti[1] + 1) val = w1;
            if (l == ti[2] + 1) val = w2;
            rw[(size_t)n * NEXP + l] = val;
        }
        if (l == 0) {
            w4[n*4+0] = 0.25f; w4[n*4+1] = w0; w4[n*4+2] = w1; w4[n*4+3] = w2;
            int e1 = ti[0] + 1, e2 = ti[1] + 1, e3 = ti[2] + 1;
            int p0 = atomicAdd(&cur[0], 1);  list[p0]             = n * 4 + 0;
            int p1 = atomicAdd(&cur[e1], 1); list[e1 * NTOK + p1] = n * 4 + 1;
            int p2 = atomicAdd(&cur[e2], 1); list[e2 * NTOK + p2] = n * 4 + 2;
            int p3 = atomicAdd(&cur[e3], 1); list[e3 * NTOK + p3] = n * 4 + 3;
        }
    } else {
        // ---------- weight shuffle part ----------
        // supertile = 32 k-rows x 64 n-cols; coalesced read -> LDS -> frag-order write
        const int w = tid >> 6;
        const int st = (bx - 1024) * 4 + w;
        unsigned short* T = (unsigned short*)SMEM + w * 32 * TP;

        const float* src; int ld; int e, kb, sn; bool isW1;
        if (st < 4096) {
            isW1 = true;
            e = st >> 7; int rem = st & 127; kb = rem >> 4; sn = rem & 15;
            src = W1 + ((size_t)(e * CDIM + kb * 32)) * HDIM + sn * 64; ld = HDIM;
        } else {
            isW1 = false;
            int s2 = st - 4096;
            e = s2 >> 7; int rem = s2 & 127; kb = rem >> 2; sn = rem & 3;
            src = W2 + ((size_t)(e * HDIM + kb * 32)) * CDIM + sn * 64; ld = CDIM;
        }
        const int rr = l >> 4, cc = (l & 15) * 4;
        #pragma unroll
        for (int i = 0; i < 8; ++i) {
            float4 v = *(const float4*)(src + (size_t)(i * 4 + rr) * ld + cc);
            ushort4 u; u.x = f2bf(v.x); u.y = f2bf(v.y); u.z = f2bf(v.z); u.w = f2bf(v.w);
            *(ushort4*)(T + (i * 4 + rr) * TP + cc) = u;
        }
        __syncthreads();
        #pragma unroll
        for (int nb2 = 0; nb2 < 4; ++nb2) {
            unsigned short t[8];
            #pragma unroll
            for (int j = 0; j < 8; ++j) t[j] = T[(q * 8 + j) * TP + nb2 * 16 + m16];
            uint4 u;
            u.x = (unsigned)t[0] | ((unsigned)t[1] << 16);
            u.y = (unsigned)t[2] | ((unsigned)t[3] << 16);
            u.z = (unsigned)t[4] | ((unsigned)t[5] << 16);
            u.w = (unsigned)t[6] | ((unsigned)t[7] << 16);
            if (isW1) {
                size_t gw = (size_t)e * 512 + (sn * 4 + nb2) * 8 + kb;
                *(uint4*)(W1s + gw * 512 + l * 8) = u;
            } else {
                size_t g2 = (size_t)e * 512 + (sn * 4 + nb2) * 32 + kb;
                *(uint4*)(W2s + g2 * 512 + l * 8) = u;
            }
        }
    }
}

// =============== grouped sparse expert FFN: 128-token tiles, chunk-per-block ===============
__launch_bounds__(256, 2)
__global__ void k_moe(const unsigned short* __restrict__ xb,
                      const unsigned short* __restrict__ W1s,
                      const float* __restrict__ b1,
                      const unsigned short* __restrict__ W2s,
                      const float* __restrict__ b2,
                      const int* __restrict__ cur, const int* __restrict__ list,
                      const float* __restrict__ w4, float* __restrict__ out)
{
    const int nc = blockIdx.x;     // hidden chunk (4)
    const int e  = blockIdx.y;     // expert (32)
    const int tile = blockIdx.z;   // token tile (32) -- slowest => same-XCD L2 weight reuse
    const int count = cur[e];
    if (tile * MT >= count) return;

    __shared__ __align__(16) unsigned short XH[MT * LDX];
    __shared__ int   stoks[MT];
    __shared__ float wgts[MT];

    const int tid = threadIdx.x, w = tid >> 6, l = tid & 63, q = l >> 4, m16 = l & 15;
    const int base = e * NTOK + tile * MT;
    const int nvalid = min(MT, count - tile * MT);

    // stage-1 weight prefetch, ks=0 (independent of token staging)
    const unsigned short* w1base = W1s + ((size_t)(e * 64 + nc * 16 + 4 * w) * 8) * 512 + l * 8;
    bf16x8 pb[4], qb[4];
    #pragma unroll
    for (int bj = 0; bj < 4; ++bj) pb[bj] = *(const bf16x8*)(w1base + bj * 4096);

    if (tid < MT) {
        if (tid < nvalid) { int a = list[base + tid]; stoks[tid] = a >> 2; wgts[tid] = w4[a]; }
        else              { stoks[tid] = 0; wgts[tid] = 0.f; }
    }
    // gather X tile: 128 rows x 256 cols bf16; thread = (row, half)
    {
        const int xrow = tid >> 1, xh = (tid & 1) * 128;
        const int a = (xrow < nvalid) ? list[base + xrow] : 0;
        const unsigned short* xr = xb + (size_t)(a >> 2) * CDIM + xh;
        unsigned short* dst = XH + xrow * LDX + xh;
        #pragma unroll
        for (int j = 0; j < 128; j += 8)
            *(uint4*)(dst + j) = *(const uint4*)(xr + j);
    }
    __syncthreads();

    const f32x4 fzero = {0.f, 0.f, 0.f, 0.f};
    f32x4 acc[8][4];
    #pragma unroll
    for (int i = 0; i < 8; ++i)
        #pragma unroll
        for (int j = 0; j < 4; ++j) acc[i][j] = fzero;

    // ---- stage 1: H = gelu(X @ W1_chunk + b1) ----
    #pragma unroll 1
    for (int ks = 0; ks < 8; ks += 2) {
        // prefetch ks+1
        #pragma unroll
        for (int bj = 0; bj < 4; ++bj) qb[bj] = *(const bf16x8*)(w1base + bj * 4096 + (ks + 1) * 512);
        {
            bf16x8 a[8];
            #pragma unroll
            for (int ai = 0; ai < 8; ++ai)
                a[ai] = *(const bf16x8*)(XH + (16*ai + m16) * LDX + ks*32 + q*8);
            #pragma unroll
            for (int ai = 0; ai < 8; ++ai)
                #pragma unroll
                for (int bj = 0; bj < 4; ++bj)
                    acc[ai][bj] = __builtin_amdgcn_mfma_f32_16x16x32_bf16(a[ai], pb[bj], acc[ai][bj], 0, 0, 0);
        }
        // prefetch ks+2 (clamped)
        const int ksn = (ks + 2 < 8) ? ks + 2 : 0;
        #pragma unroll
        for (int bj = 0; bj < 4; ++bj) pb[bj] = *(const bf16x8*)(w1base + bj * 4096 + ksn * 512);
        {
            bf16x8 a[8];
            #pragma unroll
            for (int ai = 0; ai < 8; ++ai)
                a[ai] = *(const bf16x8*)(XH + (16*ai + m16) * LDX + (ks+1)*32 + q*8);
            #pragma unroll
            for (int ai = 0; ai < 8; ++ai)
                #pragma unroll
                for (int bj = 0; bj < 4; ++bj)
                    acc[ai][bj] = __builtin_amdgcn_mfma_f32_16x16x32_bf16(a[ai], qb[bj], acc[ai][bj], 0, 0, 0);
        }
    }
    __syncthreads();   // all X reads done before overwriting XH with H

    // prefetch stage-2 ks=0 weights, then write H
    const unsigned short* w2base = W2s + ((size_t)(e * 16 + 4 * w) * 32 + nc * 8) * 512 + l * 8;
    #pragma unroll
    for (int bj = 0; bj < 4; ++bj) pb[bj] = *(const bf16x8*)(w2base + bj * 16384);

    const int hc0 = nc * 256;
    #pragma unroll
    for (int bj = 0; bj < 4; ++bj) {
        int colc = 64*w + 16*bj + m16;
        float bv = b1[e * HDIM + hc0 + colc];
        #pragma unroll
        for (int ai = 0; ai < 8; ++ai)
            #pragma unroll
            for (int r = 0; r < 4; ++r) {
                int row = 16*ai + 4*q + r;
                XH[row * LDX + colc] = f2bf(gelu_tanh(acc[ai][bj][r] + bv));
            }
    }
    __syncthreads();   // H visible to all waves

    // ---- stage 2: O = H @ W2_chunk ----
    #pragma unroll
    for (int i = 0; i < 8; ++i)
        #pragma unroll
        for (int j = 0; j < 4; ++j) acc[i][j] = fzero;

    #pragma unroll 1
    for (int ks = 0; ks < 8; ks += 2) {
        #pragma unroll
        for (int bj = 0; bj < 4; ++bj) qb[bj] = *(const bf16x8*)(w2base + bj * 16384 + (ks + 1) * 512);
        {
            bf16x8 a[8];
            #pragma unroll
            for (int ai = 0; ai < 8; ++ai)
                a[ai] = *(const bf16x8*)(XH + (16*ai + m16) * LDX + ks*32 + q*8);
            #pragma unroll
            for (int ai = 0; ai < 8; ++ai)
                #pragma unroll
                for (int bj = 0; bj < 4; ++bj)
                    acc[ai][bj] = __builtin_amdgcn_mfma_f32_16x16x32_bf16(a[ai], pb[bj], acc[ai][bj], 0, 0, 0);
        }
        const int ksn = (ks + 2 < 8) ? ks + 2 : 0;
        #pragma unroll
        for (int bj = 0; bj < 4; ++bj) pb[bj] = *(const bf16x8*)(w2base + bj * 16384 + ksn * 512);
        {
            bf16x8 a[8];
            #pragma unroll
            for (int ai = 0; ai < 8; ++ai)
                a[ai] = *(const bf16x8*)(XH + (16*ai + m16) * LDX + (ks+1)*32 + q*8);
            #pragma unroll
            for (int ai = 0; ai < 8; ++ai)
                #pragma unroll
                for (int bj = 0; bj < 4; ++bj)
                    acc[ai][bj] = __builtin_amdgcn_mfma_f32_16x16x32_bf16(a[ai], qb[bj], acc[ai][bj], 0, 0, 0);
        }
    }

    // epilogue: +b2, scale by gate weight, atomic accumulate
    #pragma unroll
    for (int bj = 0; bj < 4; ++bj) {
        int col = 64*w + 16*bj + m16;
        float b2v = b2[e * CDIM + col];
        #pragma unroll
        for (int ai = 0; ai < 8; ++ai)
            #pragma unroll
            for (int r = 0; r < 4; ++r) {
                int row = 16*ai + 4*q + r;
                float wv = wgts[row];
                if (wv != 0.f)
                    atomicAdd(out + (size_t)stoks[row] * CDIM + col, (acc[ai][bj][r] + b2v) * wv);
            }
    }
}

extern "C" void kernel_launch(void* const* d_in, const int* in_sizes, int n_in,
                              void* d_out, int out_size, void* d_ws, size_t ws_size,
                              hipStream_t stream)
{
    const float* x  = (const float*)d_in[0];
    const float* gW = (const float*)d_in[1];
    const float* gb = (const float*)d_in[2];
    const float* eb = (const float*)d_in[3];
    const float* W1 = (const float*)d_in[4];
    const float* b1 = (const float*)d_in[5];
    const float* W2 = (const float*)d_in[6];
    const float* b2 = (const float*)d_in[7];
    float* out = (float*)d_out;
    float* rw  = out + (size_t)NTOK * CDIM;   // second output: router_weights [N, 32]

    char* p = (char*)d_ws;
    int*   cur  = (int*)p;                           // 32 ints
    float* w4   = (float*)(p + 1024);                // 16384 floats
    int*   list = (int*)(p + 1024 + 65536);          // 32*4096 ints (bucketed)
    unsigned short* xbuf = (unsigned short*)(p + (1 << 20));   // 2 MB
    unsigned short* W1s  = xbuf + (size_t)NTOK * CDIM;         // 16.78 MB
    unsigned short* W2s  = W1s + (size_t)NEXP * CDIM * HDIM;   // 16.78 MB

    hipMemsetAsync(cur, 0, 128, stream);   // expert counters only

    k_prep<<<3072, 256, 0, stream>>>(x, gW, gb, eb, W1, W2,
                                     rw, xbuf, cur, list, w4, W1s, W2s, out);
    k_moe<<<dim3(4, NEXP, 32), 256, 0, stream>>>(xbuf, W1s, b1, W2s, b2, cur, list, w4, out);
}

// Round 5
// 375.151 us; speedup vs baseline: 1.2562x; 1.2562x over previous
//
#include <hip/hip_runtime.h>
#include <hip/hip_bf16.h>

#define NTOK 4096
#define CDIM 256
#define HDIM 1024
#define NEXP 32
#define MT   128
#define LDX  264   // XH row stride in shorts
#define TP   72    // cvt LDS transpose pitch (shorts)

typedef __bf16 bf16x8 __attribute__((ext_vector_type(8)));
typedef float  f32x4  __attribute__((ext_vector_type(4)));

__device__ __forceinline__ unsigned short f2bf(float f) {
    __hip_bfloat16 h = __float2bfloat16(f);
    return __builtin_bit_cast(unsigned short, h);
}

__device__ __forceinline__ float gelu_fast(float v) {
    // 0.5*v*(1+tanh(c)) == v / (1 + exp(-2c)), c = sqrt(2/pi)*(v + 0.044715 v^3)
    float c = 0.7978845608028654f * (v + 0.044715f * v * v * v);
    return v * __builtin_amdgcn_rcpf(1.f + __expf(-2.f * c));
}

// =============== mega kernel: router (+x->bf16, +out zeroing) | weight shuffle ===============
__launch_bounds__(256, 4)
__global__ void k_prep(const float* __restrict__ x, const float* __restrict__ gW,
                       const float* __restrict__ gb, const float* __restrict__ eb,
                       const float* __restrict__ W1, const float* __restrict__ W2,
                       float* __restrict__ rw, unsigned short* __restrict__ xb,
                       int* __restrict__ cur, int* __restrict__ list, float* __restrict__ w4,
                       unsigned short* __restrict__ W1s, unsigned short* __restrict__ W2s,
                       float* __restrict__ outz)
{
    __shared__ __align__(16) unsigned char SMEM[4 * 32 * TP * 2];
    const int bx = blockIdx.x, tid = threadIdx.x;
    const int l = tid & 63, q = l >> 4, m16 = l & 15;

    if (bx < 1024) {
        // ---------- router part + out zeroing ----------
        const f32x4 z4 = {0.f, 0.f, 0.f, 0.f};
        *(f32x4*)(outz + ((size_t)bx * 256 + tid) * 4) = z4;

        float* xs = (float*)SMEM;          // [4][256]
        const int wv = tid >> 6;
        const int n = bx * 4 + wv;
        const float* xr = x + (size_t)n * CDIM;
        float4 v = *(const float4*)(xr + l * 4);
        ushort4 u; u.x = f2bf(v.x); u.y = f2bf(v.y); u.z = f2bf(v.z); u.w = f2bf(v.w);
        *(ushort4*)(xb + (size_t)n * CDIM + l * 4) = u;
        *(float4*)(&xs[wv * 256 + l * 4]) = v;
        __syncthreads();

        float logit = -1e30f;
        if (l < 31) {
            float acc = 0.f;
            #pragma unroll 8
            for (int k = 0; k < CDIM; ++k) acc = fmaf(xs[wv * 256 + k], gW[k * 31 + l], acc);
            logit = acc + gb[l];
        }
        float mx = logit;
        #pragma unroll
        for (int o = 32; o; o >>= 1) mx = fmaxf(mx, __shfl_xor(mx, o));
        float p = (l < 31) ? expf(logit - mx) : 0.f;
        float s = p;
        #pragma unroll
        for (int o = 32; o; o >>= 1) s += __shfl_xor(s, o);
        float bv = (l < 31) ? p / s + eb[l] : -1e30f;
        float tv[3]; int ti[3];
        #pragma unroll
        for (int r = 0; r < 3; ++r) {
            float m = bv;
            #pragma unroll
            for (int o = 32; o; o >>= 1) m = fmaxf(m, __shfl_xor(m, o));
            unsigned long long msk = __ballot(bv == m);
            int src = __ffsll(msk) - 1;      // ties -> lowest index, matches lax.top_k
            tv[r] = m; ti[r] = src;
            if (l == src) bv = -1e30f;
        }
        float invs = 0.75f / (tv[0] + tv[1] + tv[2]);
        float w0 = tv[0] * invs, w1 = tv[1] * invs, w2 = tv[2] * invs;
        if (l < 32) {
            float val = (l == 0) ? 0.25f : 0.f;
            if (l == ti[0] + 1) val = w0;
            if (l == ti[1] + 1) val = w1;
            if (l == ti[2] + 1) val = w2;
            rw[(size_t)n * NEXP + l] = val;
        }
        if (l == 0) {
            w4[n*4+0] = 0.25f; w4[n*4+1] = w0; w4[n*4+2] = w1; w4[n*4+3] = w2;
            int e1 = ti[0] + 1, e2 = ti[1] + 1, e3 = ti[2] + 1;
            int p0 = atomicAdd(&cur[0], 1);  list[p0]             = n * 4 + 0;
            int p1 = atomicAdd(&cur[e1], 1); list[e1 * NTOK + p1] = n * 4 + 1;
            int p2 = atomicAdd(&cur[e2], 1); list[e2 * NTOK + p2] = n * 4 + 2;
            int p3 = atomicAdd(&cur[e3], 1); list[e3 * NTOK + p3] = n * 4 + 3;
        }
    } else {
        // ---------- weight shuffle: coalesced read -> LDS transpose -> frag-order write ----------
        const int w = tid >> 6;
        const int st = (bx - 1024) * 4 + w;
        unsigned short* T = (unsigned short*)SMEM + w * 32 * TP;

        const float* src; int ld; int e, kb, sn; bool isW1;
        if (st < 4096) {
            isW1 = true;
            e = st >> 7; int rem = st & 127; kb = rem >> 4; sn = rem & 15;
            src = W1 + ((size_t)(e * CDIM + kb * 32)) * HDIM + sn * 64; ld = HDIM;
        } else {
            isW1 = false;
            int s2 = st - 4096;
            e = s2 >> 7; int rem = s2 & 127; kb = rem >> 2; sn = rem & 3;
            src = W2 + ((size_t)(e * HDIM + kb * 32)) * CDIM + sn * 64; ld = CDIM;
        }
        const int rr = l >> 4, cc = (l & 15) * 4;
        #pragma unroll
        for (int i = 0; i < 8; ++i) {
            float4 v = *(const float4*)(src + (size_t)(i * 4 + rr) * ld + cc);
            ushort4 u; u.x = f2bf(v.x); u.y = f2bf(v.y); u.z = f2bf(v.z); u.w = f2bf(v.w);
            *(ushort4*)(T + (i * 4 + rr) * TP + cc) = u;
        }
        __syncthreads();
        #pragma unroll
        for (int nb2 = 0; nb2 < 4; ++nb2) {
            unsigned short t[8];
            #pragma unroll
            for (int j = 0; j < 8; ++j) t[j] = T[(q * 8 + j) * TP + nb2 * 16 + m16];
            uint4 u;
            u.x = (unsigned)t[0] | ((unsigned)t[1] << 16);
            u.y = (unsigned)t[2] | ((unsigned)t[3] << 16);
            u.z = (unsigned)t[4] | ((unsigned)t[5] << 16);
            u.w = (unsigned)t[6] | ((unsigned)t[7] << 16);
            if (isW1) {
                size_t gw = (size_t)e * 512 + (sn * 4 + nb2) * 8 + kb;
                *(uint4*)(W1s + gw * 512 + l * 8) = u;
            } else {
                size_t g2 = (size_t)e * 512 + (sn * 4 + nb2) * 32 + kb;
                *(uint4*)(W2s + g2 * 512 + l * 8) = u;
            }
        }
    }
}

// =============== persistent grouped expert FFN: 512 blocks, item loop ===============
__launch_bounds__(256, 2)
__global__ void k_moe(const unsigned short* __restrict__ xb,
                      const unsigned short* __restrict__ W1s,
                      const float* __restrict__ b1,
                      const unsigned short* __restrict__ W2s,
                      const float* __restrict__ b2,
                      const int* __restrict__ cur, const int* __restrict__ list,
                      const float* __restrict__ w4, float* __restrict__ out)
{
    __shared__ __align__(16) unsigned short XH[MT * LDX];
    __shared__ int   stoks[MT];
    __shared__ float wgts[MT];
    __shared__ int   pref[NEXP + 1];
    __shared__ int   cnts[NEXP];

    const int tid = threadIdx.x, w = tid >> 6, l = tid & 63, q = l >> 4, m16 = l & 15;

    if (tid < NEXP) cnts[tid] = cur[tid];
    __syncthreads();
    if (tid == 0) {
        int a = 0;
        for (int e = 0; e < NEXP; ++e) { pref[e] = a; a += (cnts[e] + MT - 1) >> 7; }
        pref[NEXP] = a;
    }
    __syncthreads();
    const int nitems = pref[NEXP] * 4;

    const f32x4 fzero = {0.f, 0.f, 0.f, 0.f};

    for (int it = blockIdx.x; it < nitems; it += gridDim.x) {
        const int nc = it & 3, t = it >> 2;
        int e = 0;
        while (pref[e + 1] <= t) ++e;
        const int tile = t - pref[e];
        const int count = cnts[e];
        const int base = e * NTOK + tile * MT;
        const int nvalid = min(MT, count - tile * MT);

        // issue stage-1 ks=0 weight prefetch before the barrier (overlaps prev item tail)
        const unsigned short* w1base = W1s + ((size_t)(e * 64 + nc * 16 + 4 * w) * 8) * 512 + l * 8;
        bf16x8 pb[4], qb[4];
        #pragma unroll
        for (int bj = 0; bj < 4; ++bj) pb[bj] = *(const bf16x8*)(w1base + bj * 4096);

        __syncthreads();   // prev item's readers of XH/stoks/wgts done

        if (tid < MT) {
            if (tid < nvalid) { int a = list[base + tid]; stoks[tid] = a >> 2; wgts[tid] = w4[a]; }
            else              { stoks[tid] = 0; wgts[tid] = 0.f; }
        }
        // gather X tile: 128 rows x 256 cols bf16; thread = (row, half)
        {
            const int xrow = tid >> 1, xh = (tid & 1) * 128;
            const int a = (xrow < nvalid) ? list[base + xrow] : 0;
            const unsigned short* xr = xb + (size_t)(a >> 2) * CDIM + xh;
            unsigned short* dst = XH + xrow * LDX + xh;
            #pragma unroll
            for (int j = 0; j < 128; j += 8)
                *(uint4*)(dst + j) = *(const uint4*)(xr + j);
        }
        __syncthreads();

        f32x4 acc[8][4];
        #pragma unroll
        for (int i = 0; i < 8; ++i)
            #pragma unroll
            for (int j = 0; j < 4; ++j) acc[i][j] = fzero;

        // ---- stage 1: H = gelu(X @ W1_chunk + b1) ----
        #pragma unroll 1
        for (int ks = 0; ks < 8; ks += 2) {
            #pragma unroll
            for (int bj = 0; bj < 4; ++bj) qb[bj] = *(const bf16x8*)(w1base + bj * 4096 + (ks + 1) * 512);
            {
                bf16x8 a[8];
                #pragma unroll
                for (int ai = 0; ai < 8; ++ai)
                    a[ai] = *(const bf16x8*)(XH + (16*ai + m16) * LDX + ks*32 + q*8);
                #pragma unroll
                for (int ai = 0; ai < 8; ++ai)
                    #pragma unroll
                    for (int bj = 0; bj < 4; ++bj)
                        acc[ai][bj] = __builtin_amdgcn_mfma_f32_16x16x32_bf16(a[ai], pb[bj], acc[ai][bj], 0, 0, 0);
            }
            const int ksn = (ks + 2 < 8) ? ks + 2 : 0;
            #pragma unroll
            for (int bj = 0; bj < 4; ++bj) pb[bj] = *(const bf16x8*)(w1base + bj * 4096 + ksn * 512);
            {
                bf16x8 a[8];
                #pragma unroll
                for (int ai = 0; ai < 8; ++ai)
                    a[ai] = *(const bf16x8*)(XH + (16*ai + m16) * LDX + (ks+1)*32 + q*8);
                #pragma unroll
                for (int ai = 0; ai < 8; ++ai)
                    #pragma unroll
                    for (int bj = 0; bj < 4; ++bj)
                        acc[ai][bj] = __builtin_amdgcn_mfma_f32_16x16x32_bf16(a[ai], qb[bj], acc[ai][bj], 0, 0, 0);
            }
        }
        __syncthreads();   // all X reads done before overwriting XH with H

        // prefetch stage-2 ks=0 weights, then write H (fast gelu)
        const unsigned short* w2base = W2s + ((size_t)(e * 16 + 4 * w) * 32 + nc * 8) * 512 + l * 8;
        #pragma unroll
        for (int bj = 0; bj < 4; ++bj) pb[bj] = *(const bf16x8*)(w2base + bj * 16384);

        const int hc0 = nc * 256;
        #pragma unroll
        for (int bj = 0; bj < 4; ++bj) {
            int colc = 64*w + 16*bj + m16;
            float bv = b1[e * HDIM + hc0 + colc];
            #pragma unroll
            for (int ai = 0; ai < 8; ++ai)
                #pragma unroll
                for (int r = 0; r < 4; ++r) {
                    int row = 16*ai + 4*q + r;
                    XH[row * LDX + colc] = f2bf(gelu_fast(acc[ai][bj][r] + bv));
                }
        }
        __syncthreads();   // H visible to all waves

        // ---- stage 2: O = H @ W2_chunk ----
        #pragma unroll
        for (int i = 0; i < 8; ++i)
            #pragma unroll
            for (int j = 0; j < 4; ++j) acc[i][j] = fzero;

        #pragma unroll 1
        for (int ks = 0; ks < 8; ks += 2) {
            #pragma unroll
            for (int bj = 0; bj < 4; ++bj) qb[bj] = *(const bf16x8*)(w2base + bj * 16384 + (ks + 1) * 512);
            {
                bf16x8 a[8];
                #pragma unroll
                for (int ai = 0; ai < 8; ++ai)
                    a[ai] = *(const bf16x8*)(XH + (16*ai + m16) * LDX + ks*32 + q*8);
                #pragma unroll
                for (int ai = 0; ai < 8; ++ai)
                    #pragma unroll
                    for (int bj = 0; bj < 4; ++bj)
                        acc[ai][bj] = __builtin_amdgcn_mfma_f32_16x16x32_bf16(a[ai], pb[bj], acc[ai][bj], 0, 0, 0);
            }
            const int ksn = (ks + 2 < 8) ? ks + 2 : 0;
            #pragma unroll
            for (int bj = 0; bj < 4; ++bj) pb[bj] = *(const bf16x8*)(w2base + bj * 16384 + ksn * 512);
            {
                bf16x8 a[8];
                #pragma unroll
                for (int ai = 0; ai < 8; ++ai)
                    a[ai] = *(const bf16x8*)(XH + (16*ai + m16) * LDX + (ks+1)*32 + q*8);
                #pragma unroll
                for (int ai = 0; ai < 8; ++ai)
                    #pragma unroll
                    for (int bj = 0; bj < 4; ++bj)
                        acc[ai][bj] = __builtin_amdgcn_mfma_f32_16x16x32_bf16(a[ai], qb[bj], acc[ai][bj], 0, 0, 0);
            }
        }

        // epilogue: +b2, scale by gate weight, atomic accumulate
        #pragma unroll
        for (int bj = 0; bj < 4; ++bj) {
            int col = 64*w + 16*bj + m16;
            float b2v = b2[e * CDIM + col];
            #pragma unroll
            for (int ai = 0; ai < 8; ++ai)
                #pragma unroll
                for (int r = 0; r < 4; ++r) {
                    int row = 16*ai + 4*q + r;
                    float wv = wgts[row];
                    if (wv != 0.f)
                        atomicAdd(out + (size_t)stoks[row] * CDIM + col, (acc[ai][bj][r] + b2v) * wv);
                }
        }
    }
}

extern "C" void kernel_launch(void* const* d_in, const int* in_sizes, int n_in,
                              void* d_out, int out_size, void* d_ws, size_t ws_size,
                              hipStream_t stream)
{
    const float* x  = (const float*)d_in[0];
    const float* gW = (const float*)d_in[1];
    const float* gb = (const float*)d_in[2];
    const float* eb = (const float*)d_in[3];
    const float* W1 = (const float*)d_in[4];
    const float* b1 = (const float*)d_in[5];
    const float* W2 = (const float*)d_in[6];
    const float* b2 = (const float*)d_in[7];
    float* out = (float*)d_out;
    float* rw  = out + (size_t)NTOK * CDIM;   // second output: router_weights [N, 32]

    char* p = (char*)d_ws;
    int*   cur  = (int*)p;                           // 32 ints
    float* w4   = (float*)(p + 1024);                // 16384 floats
    int*   list = (int*)(p + 1024 + 65536);          // 32*4096 ints (bucketed)
    unsigned short* xbuf = (unsigned short*)(p + (1 << 20));   // 2 MB
    unsigned short* W1s  = xbuf + (size_t)NTOK * CDIM;         // 16.78 MB
    unsigned short* W2s  = W1s + (size_t)NEXP * CDIM * HDIM;   // 16.78 MB

    hipMemsetAsync(cur, 0, 128, stream);   // expert counters only

    k_prep<<<3072, 256, 0, stream>>>(x, gW, gb, eb, W1, W2,
                                     rw, xbuf, cur, list, w4, W1s, W2s, out);
    k_moe<<<512, 256, 0, stream>>>(xbuf, W1s, b1, W2s, b2, cur, list, w4, out);
}

// Round 6
// 257.387 us; speedup vs baseline: 1.8309x; 1.4575x over previous
//
#include <hip/hip_runtime.h>
#include <hip/hip_bf16.h>

#define NTOK 4096
#define CDIM 256
#define HDIM 1024
#define NEXP 32
#define MT   128
#define LDX  264   // XH row stride in shorts
#define TP   72    // cvt LDS transpose pitch (shorts)
#define NCPY 8     // counter shards (one per XCD-ish)
#define SEG  512   // tokens per shard segment (4096/8)

typedef __bf16 bf16x8 __attribute__((ext_vector_type(8)));
typedef float  f32x4  __attribute__((ext_vector_type(4)));

__device__ __forceinline__ unsigned short f2bf(float f) {
    __hip_bfloat16 h = __float2bfloat16(f);
    return __builtin_bit_cast(unsigned short, h);
}

__device__ __forceinline__ float gelu_fast(float v) {
    // 0.5*v*(1+tanh(c)) == v / (1 + exp(-2c)), c = sqrt(2/pi)*(v + 0.044715 v^3)
    float c = 0.7978845608028654f * (v + 0.044715f * v * v * v);
    return v * __builtin_amdgcn_rcpf(1.f + __expf(-2.f * c));
}

// =============== mega kernel: router (+x->bf16, +out zeroing) | weight shuffle ===============
__launch_bounds__(256, 4)
__global__ void k_prep(const float* __restrict__ x, const float* __restrict__ gW,
                       const float* __restrict__ gb, const float* __restrict__ eb,
                       const float* __restrict__ W1, const float* __restrict__ W2,
                       float* __restrict__ rw, unsigned short* __restrict__ xb,
                       int* __restrict__ cnt8, int* __restrict__ list, float* __restrict__ w4,
                       unsigned short* __restrict__ W1s, unsigned short* __restrict__ W2s,
                       float* __restrict__ outz)
{
    __shared__ __align__(16) unsigned char SMEM[4 * 32 * TP * 2];
    const int bx = blockIdx.x, tid = threadIdx.x;
    const int l = tid & 63, q = l >> 4, m16 = l & 15;

    if (bx < 1024) {
        // ---------- router part + out zeroing ----------
        const f32x4 z4 = {0.f, 0.f, 0.f, 0.f};
        *(f32x4*)(outz + ((size_t)bx * 256 + tid) * 4) = z4;

        float* xs = (float*)SMEM;          // [4][256]
        const int wv = tid >> 6;
        const int n = bx * 4 + wv;
        const float* xr = x + (size_t)n * CDIM;
        float4 v = *(const float4*)(xr + l * 4);
        ushort4 u; u.x = f2bf(v.x); u.y = f2bf(v.y); u.z = f2bf(v.z); u.w = f2bf(v.w);
        *(ushort4*)(xb + (size_t)n * CDIM + l * 4) = u;
        *(float4*)(&xs[wv * 256 + l * 4]) = v;
        __syncthreads();

        float logit = -1e30f;
        if (l < 31) {
            float acc = 0.f;
            #pragma unroll 8
            for (int k = 0; k < CDIM; ++k) acc = fmaf(xs[wv * 256 + k], gW[k * 31 + l], acc);
            logit = acc + gb[l];
        }
        float mx = logit;
        #pragma unroll
        for (int o = 32; o; o >>= 1) mx = fmaxf(mx, __shfl_xor(mx, o));
        float p = (l < 31) ? expf(logit - mx) : 0.f;
        float s = p;
        #pragma unroll
        for (int o = 32; o; o >>= 1) s += __shfl_xor(s, o);
        float bv = (l < 31) ? p / s + eb[l] : -1e30f;
        float tv[3]; int ti[3];
        #pragma unroll
        for (int r = 0; r < 3; ++r) {
            float m = bv;
            #pragma unroll
            for (int o = 32; o; o >>= 1) m = fmaxf(m, __shfl_xor(m, o));
            unsigned long long msk = __ballot(bv == m);
            int src = __ffsll(msk) - 1;      // ties -> lowest index, matches lax.top_k
            tv[r] = m; ti[r] = src;
            if (l == src) bv = -1e30f;
        }
        float invs = 0.75f / (tv[0] + tv[1] + tv[2]);
        float w0 = tv[0] * invs, w1 = tv[1] * invs, w2 = tv[2] * invs;
        if (l < 32) {
            float val = (l == 0) ? 0.25f : 0.f;
            if (l == ti[0] + 1) val = w0;
            if (l == ti[1] + 1) val = w1;
            if (l == ti[2] + 1) val = w2;
            rw[(size_t)n * NEXP + l] = val;
        }
        if (l == 0) {
            w4[n*4+0] = 0.25f; w4[n*4+1] = w0; w4[n*4+2] = w1; w4[n*4+3] = w2;
            // expert 0: identity slot (no atomic, no list write needed)
            // routed experts: sharded, line-padded counters
            const int c = bx & (NCPY - 1);
            #pragma unroll
            for (int sslot = 1; sslot <= 3; ++sslot) {
                int e = ti[sslot - 1] + 1;
                int pos = atomicAdd(&cnt8[((e - 1) * NCPY + c) * 32], 1);
                list[e * NTOK + c * SEG + pos] = n * 4 + sslot;
            }
        }
    } else {
        // ---------- weight shuffle: coalesced read -> LDS transpose -> frag-order write ----------
        const int w = tid >> 6;
        const int st = (bx - 1024) * 4 + w;
        unsigned short* T = (unsigned short*)SMEM + w * 32 * TP;

        const float* src; int ld; int e, kb, sn; bool isW1;
        if (st < 4096) {
            isW1 = true;
            e = st >> 7; int rem = st & 127; kb = rem >> 4; sn = rem & 15;
            src = W1 + ((size_t)(e * CDIM + kb * 32)) * HDIM + sn * 64; ld = HDIM;
        } else {
            isW1 = false;
            int s2 = st - 4096;
            e = s2 >> 7; int rem = s2 & 127; kb = rem >> 2; sn = rem & 3;
            src = W2 + ((size_t)(e * HDIM + kb * 32)) * CDIM + sn * 64; ld = CDIM;
        }
        const int rr = l >> 4, cc = (l & 15) * 4;
        #pragma unroll
        for (int i = 0; i < 8; ++i) {
            float4 v = *(const float4*)(src + (size_t)(i * 4 + rr) * ld + cc);
            ushort4 u; u.x = f2bf(v.x); u.y = f2bf(v.y); u.z = f2bf(v.z); u.w = f2bf(v.w);
            *(ushort4*)(T + (i * 4 + rr) * TP + cc) = u;
        }
        __syncthreads();
        #pragma unroll
        for (int nb2 = 0; nb2 < 4; ++nb2) {
            unsigned short t[8];
            #pragma unroll
            for (int j = 0; j < 8; ++j) t[j] = T[(q * 8 + j) * TP + nb2 * 16 + m16];
            uint4 u;
            u.x = (unsigned)t[0] | ((unsigned)t[1] << 16);
            u.y = (unsigned)t[2] | ((unsigned)t[3] << 16);
            u.z = (unsigned)t[4] | ((unsigned)t[5] << 16);
            u.w = (unsigned)t[6] | ((unsigned)t[7] << 16);
            if (isW1) {
                size_t gw = (size_t)e * 512 + (sn * 4 + nb2) * 8 + kb;
                *(uint4*)(W1s + gw * 512 + l * 8) = u;
            } else {
                size_t g2 = (size_t)e * 512 + (sn * 4 + nb2) * 32 + kb;
                *(uint4*)(W2s + g2 * 512 + l * 8) = u;
            }
        }
    }
}

// =============== persistent grouped expert FFN: 512 blocks, item loop ===============
__launch_bounds__(256, 2)
__global__ void k_moe(const unsigned short* __restrict__ xb,
                      const unsigned short* __restrict__ W1s,
                      const float* __restrict__ b1,
                      const unsigned short* __restrict__ W2s,
                      const float* __restrict__ b2,
                      const int* __restrict__ cnt8, const int* __restrict__ list,
                      const float* __restrict__ w4, float* __restrict__ out)
{
    __shared__ __align__(16) unsigned short XH[MT * LDX];
    __shared__ int   stoks[MT];
    __shared__ float wgts[MT];
    __shared__ int   pref[NEXP + 1];
    __shared__ int   cnts[NEXP];
    __shared__ int   cpre[NEXP - 1][NCPY + 1];   // routed experts' shard prefixes

    const int tid = threadIdx.x, w = tid >> 6, l = tid & 63, q = l >> 4, m16 = l & 15;

    if (tid < NEXP - 1) {
        int a = 0;
        cpre[tid][0] = 0;
        #pragma unroll
        for (int c = 0; c < NCPY; ++c) {
            a += cnt8[(tid * NCPY + c) * 32];
            cpre[tid][c + 1] = a;
        }
        cnts[tid + 1] = a;
    }
    if (tid == NEXP - 1) cnts[0] = NTOK;
    __syncthreads();
    if (tid == 0) {
        int a = 0;
        for (int e = 0; e < NEXP; ++e) { pref[e] = a; a += (cnts[e] + MT - 1) >> 7; }
        pref[NEXP] = a;
    }
    __syncthreads();
    const int nitems = pref[NEXP] * 4;

    const f32x4 fzero = {0.f, 0.f, 0.f, 0.f};

    for (int it = blockIdx.x; it < nitems; it += gridDim.x) {
        const int nc = it & 3, t = it >> 2;
        int e = 0;
        while (pref[e + 1] <= t) ++e;
        const int tile = t - pref[e];
        const int count = cnts[e];
        const int base = e * NTOK + tile * MT;
        const int nvalid = min(MT, count - tile * MT);

        // issue stage-1 ks=0 weight prefetch before the barrier (overlaps prev item tail)
        const unsigned short* w1base = W1s + ((size_t)(e * 64 + nc * 16 + 4 * w) * 8) * 512 + l * 8;
        bf16x8 pb[4], qb[4];
        #pragma unroll
        for (int bj = 0; bj < 4; ++bj) pb[bj] = *(const bf16x8*)(w1base + bj * 4096);

        __syncthreads();   // prev item's readers of XH/stoks/wgts done

        if (tid < MT) {
            int a = 0;
            if (tid < nvalid) {
                int pp = tile * MT + tid;
                if (e == 0) a = pp << 2;
                else {
                    int c = 0;
                    while (cpre[e - 1][c + 1] <= pp) ++c;
                    a = list[base - tile * MT + c * SEG + (pp - cpre[e - 1][c])];
                }
                stoks[tid] = a >> 2; wgts[tid] = w4[a];
            } else { stoks[tid] = 0; wgts[tid] = 0.f; }
        }
        // gather X tile: 128 rows x 256 cols bf16; thread = (row, half)
        {
            const int xrow = tid >> 1, xh = (tid & 1) * 128;
            int a = 0;
            if (xrow < nvalid) {
                int pp = tile * MT + xrow;
                if (e == 0) a = pp << 2;
                else {
                    int c = 0;
                    while (cpre[e - 1][c + 1] <= pp) ++c;
                    a = list[e * NTOK + c * SEG + (pp - cpre[e - 1][c])];
                }
            }
            const unsigned short* xr = xb + (size_t)(a >> 2) * CDIM + xh;
            unsigned short* dst = XH + xrow * LDX + xh;
            #pragma unroll
            for (int j = 0; j < 128; j += 8)
                *(uint4*)(dst + j) = *(const uint4*)(xr + j);
        }
        __syncthreads();

        f32x4 acc[8][4];
        #pragma unroll
        for (int i = 0; i < 8; ++i)
            #pragma unroll
            for (int j = 0; j < 4; ++j) acc[i][j] = fzero;

        // ---- stage 1: H = gelu(X @ W1_chunk + b1) ----
        #pragma unroll 1
        for (int ks = 0; ks < 8; ks += 2) {
            #pragma unroll
            for (int bj = 0; bj < 4; ++bj) qb[bj] = *(const bf16x8*)(w1base + bj * 4096 + (ks + 1) * 512);
            {
                bf16x8 a[8];
                #pragma unroll
                for (int ai = 0; ai < 8; ++ai)
                    a[ai] = *(const bf16x8*)(XH + (16*ai + m16) * LDX + ks*32 + q*8);
                #pragma unroll
                for (int ai = 0; ai < 8; ++ai)
                    #pragma unroll
                    for (int bj = 0; bj < 4; ++bj)
                        acc[ai][bj] = __builtin_amdgcn_mfma_f32_16x16x32_bf16(a[ai], pb[bj], acc[ai][bj], 0, 0, 0);
            }
            const int ksn = (ks + 2 < 8) ? ks + 2 : 0;
            #pragma unroll
            for (int bj = 0; bj < 4; ++bj) pb[bj] = *(const bf16x8*)(w1base + bj * 4096 + ksn * 512);
            {
                bf16x8 a[8];
                #pragma unroll
                for (int ai = 0; ai < 8; ++ai)
                    a[ai] = *(const bf16x8*)(XH + (16*ai + m16) * LDX + (ks+1)*32 + q*8);
                #pragma unroll
                for (int ai = 0; ai < 8; ++ai)
                    #pragma unroll
                    for (int bj = 0; bj < 4; ++bj)
                        acc[ai][bj] = __builtin_amdgcn_mfma_f32_16x16x32_bf16(a[ai], qb[bj], acc[ai][bj], 0, 0, 0);
            }
        }
        __syncthreads();   // all X reads done before overwriting XH with H

        // prefetch stage-2 ks=0 weights, then write H (fast gelu)
        const unsigned short* w2base = W2s + ((size_t)(e * 16 + 4 * w) * 32 + nc * 8) * 512 + l * 8;
        #pragma unroll
        for (int bj = 0; bj < 4; ++bj) pb[bj] = *(const bf16x8*)(w2base + bj * 16384);

        const int hc0 = nc * 256;
        #pragma unroll
        for (int bj = 0; bj < 4; ++bj) {
            int colc = 64*w + 16*bj + m16;
            float bv = b1[e * HDIM + hc0 + colc];
            #pragma unroll
            for (int ai = 0; ai < 8; ++ai)
                #pragma unroll
                for (int r = 0; r < 4; ++r) {
                    int row = 16*ai + 4*q + r;
                    XH[row * LDX + colc] = f2bf(gelu_fast(acc[ai][bj][r] + bv));
                }
        }
        __syncthreads();   // H visible to all waves

        // ---- stage 2: O = H @ W2_chunk ----
        #pragma unroll
        for (int i = 0; i < 8; ++i)
            #pragma unroll
            for (int j = 0; j < 4; ++j) acc[i][j] = fzero;

        #pragma unroll 1
        for (int ks = 0; ks < 8; ks += 2) {
            #pragma unroll
            for (int bj = 0; bj < 4; ++bj) qb[bj] = *(const bf16x8*)(w2base + bj * 16384 + (ks + 1) * 512);
            {
                bf16x8 a[8];
                #pragma unroll
                for (int ai = 0; ai < 8; ++ai)
                    a[ai] = *(const bf16x8*)(XH + (16*ai + m16) * LDX + ks*32 + q*8);
                #pragma unroll
                for (int ai = 0; ai < 8; ++ai)
                    #pragma unroll
                    for (int bj = 0; bj < 4; ++bj)
                        acc[ai][bj] = __builtin_amdgcn_mfma_f32_16x16x32_bf16(a[ai], pb[bj], acc[ai][bj], 0, 0, 0);
            }
            const int ksn = (ks + 2 < 8) ? ks + 2 : 0;
            #pragma unroll
            for (int bj = 0; bj < 4; ++bj) pb[bj] = *(const bf16x8*)(w2base + bj * 16384 + ksn * 512);
            {
                bf16x8 a[8];
                #pragma unroll
                for (int ai = 0; ai < 8; ++ai)
                    a[ai] = *(const bf16x8*)(XH + (16*ai + m16) * LDX + (ks+1)*32 + q*8);
                #pragma unroll
                for (int ai = 0; ai < 8; ++ai)
                    #pragma unroll
                    for (int bj = 0; bj < 4; ++bj)
                        acc[ai][bj] = __builtin_amdgcn_mfma_f32_16x16x32_bf16(a[ai], qb[bj], acc[ai][bj], 0, 0, 0);
            }
        }

        // epilogue: +b2, scale by gate weight, atomic accumulate
        #pragma unroll
        for (int bj = 0; bj < 4; ++bj) {
            int col = 64*w + 16*bj + m16;
            float b2v = b2[e * CDIM + col];
            #pragma unroll
            for (int ai = 0; ai < 8; ++ai)
                #pragma unroll
                for (int r = 0; r < 4; ++r) {
                    int row = 16*ai + 4*q + r;
                    float wv = wgts[row];
                    if (wv != 0.f)
                        atomicAdd(out + (size_t)stoks[row] * CDIM + col, (acc[ai][bj][r] + b2v) * wv);
                }
        }
    }
}

extern "C" void kernel_launch(void* const* d_in, const int* in_sizes, int n_in,
                              void* d_out, int out_size, void* d_ws, size_t ws_size,
                              hipStream_t stream)
{
    const float* x  = (const float*)d_in[0];
    const float* gW = (const float*)d_in[1];
    const float* gb = (const float*)d_in[2];
    const float* eb = (const float*)d_in[3];
    const float* W1 = (const float*)d_in[4];
    const float* b1 = (const float*)d_in[5];
    const float* W2 = (const float*)d_in[6];
    const float* b2 = (const float*)d_in[7];
    float* out = (float*)d_out;
    float* rw  = out + (size_t)NTOK * CDIM;   // second output: router_weights [N, 32]

    char* p = (char*)d_ws;
    int*   cnt8 = (int*)p;                           // 31*8 line-padded counters (32 KB)
    float* w4   = (float*)(p + 32768);               // 16384 floats
    int*   list = (int*)(p + 32768 + 65536);         // 32*4096 ints (sharded buckets)
    unsigned short* xbuf = (unsigned short*)(p + (1 << 20));   // 2 MB
    unsigned short* W1s  = xbuf + (size_t)NTOK * CDIM;         // 16.78 MB
    unsigned short* W2s  = W1s + (size_t)NEXP * CDIM * HDIM;   // 16.78 MB

    hipMemsetAsync(cnt8, 0, 32768, stream);   // sharded expert counters

    k_prep<<<3072, 256, 0, stream>>>(x, gW, gb, eb, W1, W2,
                                     rw, xbuf, cnt8, list, w4, W1s, W2s, out);
    k_moe<<<512, 256, 0, stream>>>(xbuf, W1s, b1, W2s, b2, cnt8, list, w4, out);
}

// Round 7
// 178.477 us; speedup vs baseline: 2.6404x; 1.4421x over previous
//
#include <hip/hip_runtime.h>
#include <hip/hip_bf16.h>

#define NTOK 4096
#define CDIM 256
#define HDIM 1024
#define NEXP 32
#define MT   64
#define LDX  264    // X/H row stride in shorts
#define TP   72     // cvt LDS transpose pitch (shorts)
#define NCPY 8      // counter shards
#define SEG  512    // tokens per shard segment
#define DUMP 16384  // dump slot for padded rows
#define SROWS (DUMP + 1)

typedef __bf16 bf16x8 __attribute__((ext_vector_type(8)));
typedef float  f32x4  __attribute__((ext_vector_type(4)));

__device__ __forceinline__ unsigned short f2bf(float f) {
    __hip_bfloat16 h = __float2bfloat16(f);
    return __builtin_bit_cast(unsigned short, h);
}

__device__ __forceinline__ float gelu_fast(float v) {
    float c = 0.7978845608028654f * (v + 0.044715f * v * v * v);
    return v * __builtin_amdgcn_rcpf(1.f + __expf(-2.f * c));
}

// =============== mega kernel: router (+x->bf16) | weight shuffle ===============
__launch_bounds__(256, 4)
__global__ void k_prep(const float* __restrict__ x, const float* __restrict__ gW,
                       const float* __restrict__ gb, const float* __restrict__ eb,
                       const float* __restrict__ W1, const float* __restrict__ W2,
                       float* __restrict__ rw, unsigned short* __restrict__ xb,
                       int* __restrict__ cnt8, int* __restrict__ list, float* __restrict__ w4,
                       unsigned short* __restrict__ W1s, unsigned short* __restrict__ W2s)
{
    __shared__ __align__(16) unsigned char SMEM[4 * 32 * TP * 2];
    const int bx = blockIdx.x, tid = threadIdx.x;
    const int l = tid & 63, q = l >> 4, m16 = l & 15;

    if (bx < 1024) {
        // ---------- router ----------
        float* xs = (float*)SMEM;          // [4][256]
        const int wv = tid >> 6;
        const int n = bx * 4 + wv;
        const float* xr = x + (size_t)n * CDIM;
        float4 v = *(const float4*)(xr + l * 4);
        ushort4 u; u.x = f2bf(v.x); u.y = f2bf(v.y); u.z = f2bf(v.z); u.w = f2bf(v.w);
        *(ushort4*)(xb + (size_t)n * CDIM + l * 4) = u;
        *(float4*)(&xs[wv * 256 + l * 4]) = v;
        __syncthreads();

        float logit = -1e30f;
        if (l < 31) {
            float acc = 0.f;
            #pragma unroll 8
            for (int k = 0; k < CDIM; ++k) acc = fmaf(xs[wv * 256 + k], gW[k * 31 + l], acc);
            logit = acc + gb[l];
        }
        float mx = logit;
        #pragma unroll
        for (int o = 32; o; o >>= 1) mx = fmaxf(mx, __shfl_xor(mx, o));
        float p = (l < 31) ? expf(logit - mx) : 0.f;
        float s = p;
        #pragma unroll
        for (int o = 32; o; o >>= 1) s += __shfl_xor(s, o);
        float bv = (l < 31) ? p / s + eb[l] : -1e30f;
        float tv[3]; int ti[3];
        #pragma unroll
        for (int r = 0; r < 3; ++r) {
            float m = bv;
            #pragma unroll
            for (int o = 32; o; o >>= 1) m = fmaxf(m, __shfl_xor(m, o));
            unsigned long long msk = __ballot(bv == m);
            int src = __ffsll(msk) - 1;      // ties -> lowest index, matches lax.top_k
            tv[r] = m; ti[r] = src;
            if (l == src) bv = -1e30f;
        }
        float invs = 0.75f / (tv[0] + tv[1] + tv[2]);
        float w0 = tv[0] * invs, w1 = tv[1] * invs, w2 = tv[2] * invs;
        if (l < 32) {
            float val = (l == 0) ? 0.25f : 0.f;
            if (l == ti[0] + 1) val = w0;
            if (l == ti[1] + 1) val = w1;
            if (l == ti[2] + 1) val = w2;
            rw[(size_t)n * NEXP + l] = val;
        }
        if (l == 0) {
            w4[n*4+0] = 0.25f; w4[n*4+1] = w0; w4[n*4+2] = w1; w4[n*4+3] = w2;
            const int c = bx & (NCPY - 1);
            #pragma unroll
            for (int sslot = 1; sslot <= 3; ++sslot) {
                int e = ti[sslot - 1] + 1;
                int pos = atomicAdd(&cnt8[((e - 1) * NCPY + c) * 32], 1);
                list[e * NTOK + c * SEG + pos] = n * 4 + sslot;
            }
        }
    } else {
        // ---------- weight shuffle ----------
        const int w = tid >> 6;
        const int st = (bx - 1024) * 4 + w;
        unsigned short* T = (unsigned short*)SMEM + w * 32 * TP;

        const float* src; int ld; int e, kb, sn; bool isW1;
        if (st < 4096) {
            isW1 = true;
            e = st >> 7; int rem = st & 127; kb = rem >> 4; sn = rem & 15;
            src = W1 + ((size_t)(e * CDIM + kb * 32)) * HDIM + sn * 64; ld = HDIM;
        } else {
            isW1 = false;
            int s2 = st - 4096;
            e = s2 >> 7; int rem = s2 & 127; kb = rem >> 2; sn = rem & 3;
            src = W2 + ((size_t)(e * HDIM + kb * 32)) * CDIM + sn * 64; ld = CDIM;
        }
        const int rr = l >> 4, cc = (l & 15) * 4;
        #pragma unroll
        for (int i = 0; i < 8; ++i) {
            float4 v = *(const float4*)(src + (size_t)(i * 4 + rr) * ld + cc);
            ushort4 u; u.x = f2bf(v.x); u.y = f2bf(v.y); u.z = f2bf(v.z); u.w = f2bf(v.w);
            *(ushort4*)(T + (i * 4 + rr) * TP + cc) = u;
        }
        __syncthreads();
        #pragma unroll
        for (int nb2 = 0; nb2 < 4; ++nb2) {
            unsigned short t[8];
            #pragma unroll
            for (int j = 0; j < 8; ++j) t[j] = T[(q * 8 + j) * TP + nb2 * 16 + m16];
            uint4 u;
            u.x = (unsigned)t[0] | ((unsigned)t[1] << 16);
            u.y = (unsigned)t[2] | ((unsigned)t[3] << 16);
            u.z = (unsigned)t[4] | ((unsigned)t[5] << 16);
            u.w = (unsigned)t[6] | ((unsigned)t[7] << 16);
            if (isW1) {
                size_t gw = (size_t)e * 512 + (sn * 4 + nb2) * 8 + kb;
                *(uint4*)(W1s + gw * 512 + l * 8) = u;
            } else {
                size_t g2 = (size_t)e * 512 + (sn * 4 + nb2) * 32 + kb;
                *(uint4*)(W2s + g2 * 512 + l * 8) = u;
            }
        }
    }
}

// =============== persistent expert FFN: items = (token-tile, hidden-half), no atomics ===============
__launch_bounds__(256, 2)
__global__ void k_moe(const unsigned short* __restrict__ xb,
                      const unsigned short* __restrict__ W1s,
                      const float* __restrict__ b1,
                      const unsigned short* __restrict__ W2s,
                      const float* __restrict__ b2,
                      const int* __restrict__ cnt8, const int* __restrict__ list,
                      const float* __restrict__ w4, float* __restrict__ scratch)
{
    __shared__ __align__(16) unsigned short Xb[MT * LDX];
    __shared__ __align__(16) unsigned short Hb[MT * LDX];
    __shared__ float wgts[MT];
    __shared__ int   srow[MT];
    __shared__ int   pref[NEXP + 1];
    __shared__ int   cnts[NEXP];
    __shared__ int   cpre[NEXP - 1][NCPY + 1];

    const int tid = threadIdx.x, w = tid >> 6, l = tid & 63, q = l >> 4, m16 = l & 15;

    if (tid < NEXP - 1) {
        int a = 0;
        cpre[tid][0] = 0;
        #pragma unroll
        for (int c = 0; c < NCPY; ++c) {
            a += cnt8[(tid * NCPY + c) * 32];
            cpre[tid][c + 1] = a;
        }
        cnts[tid + 1] = a;
    }
    if (tid == NEXP - 1) cnts[0] = NTOK;
    __syncthreads();
    if (tid == 0) {
        int a = 0;
        for (int e = 0; e < NEXP; ++e) { pref[e] = a; a += (cnts[e] + MT - 1) >> 6; }
        pref[NEXP] = a;
    }
    __syncthreads();
    const int nitems = pref[NEXP] * 2;

    const f32x4 fzero = {0.f, 0.f, 0.f, 0.f};

    for (int it = blockIdx.x; it < nitems; it += gridDim.x) {
        const int c2 = it & 1, t = it >> 1;
        int e = 0;
        while (pref[e + 1] <= t) ++e;
        const int tile = t - pref[e];
        const int nvalid = min(MT, cnts[e] - tile * MT);
        const int nc0 = c2 * 2;

        // preload stage-1(nc0) ks=0..2 weight frags under the top barrier
        const unsigned short* w1n = W1s + ((size_t)(e * 64 + nc0 * 16 + 4 * w) * 8) * 512 + l * 8;
        bf16x8 wb[3][4];
        #pragma unroll
        for (int k = 0; k < 3; ++k)
            #pragma unroll
            for (int bj = 0; bj < 4; ++bj)
                wb[k][bj] = *(const bf16x8*)(w1n + bj * 4096 + k * 512);

        __syncthreads();   // prev item's readers of Xb/Hb/wgts/srow done

        if (tid < MT) {
            float wv = 0.f; int sa = DUMP;
            if (tid < nvalid) {
                int pp = tile * MT + tid, a;
                if (e == 0) a = pp << 2;
                else {
                    int c = 0;
                    while (cpre[e - 1][c + 1] <= pp) ++c;
                    a = list[e * NTOK + c * SEG + (pp - cpre[e - 1][c])];
                }
                sa = a; wv = w4[a];
            }
            srow[tid] = sa; wgts[tid] = wv;
        }
        // gather X tile: 64 rows x 256 cols bf16
        {
            const int xrow = tid >> 2, seg = (tid & 3) * 64;
            int a = 0;
            if (xrow < nvalid) {
                int pp = tile * MT + xrow;
                if (e == 0) a = pp << 2;
                else {
                    int c = 0;
                    while (cpre[e - 1][c + 1] <= pp) ++c;
                    a = list[e * NTOK + c * SEG + (pp - cpre[e - 1][c])];
                }
            }
            const unsigned short* xr = xb + (size_t)(a >> 2) * CDIM + seg;
            unsigned short* dst = Xb + xrow * LDX + seg;
            #pragma unroll
            for (int j = 0; j < 64; j += 8)
                *(uint4*)(dst + j) = *(const uint4*)(xr + j);
        }
        __syncthreads();

        f32x4 acc[4][4];
        #pragma unroll
        for (int i = 0; i < 4; ++i)
            #pragma unroll
            for (int j = 0; j < 4; ++j) acc[i][j] = fzero;

        #pragma unroll
        for (int hc = 0; hc < 2; ++hc) {
            const int nc = nc0 + hc;
            const unsigned short* w1c = W1s + ((size_t)(e * 64 + nc * 16 + 4 * w) * 8) * 512 + l * 8;
            const unsigned short* w2c = W2s + ((size_t)(e * 16 + 4 * w) * 32 + nc * 8) * 512 + l * 8;

            // ---- stage 1: Hc = gelu(X @ W1[nc] + b1) ----
            f32x4 hacc[4][4];
            #pragma unroll
            for (int i = 0; i < 4; ++i)
                #pragma unroll
                for (int j = 0; j < 4; ++j) hacc[i][j] = fzero;

            #pragma unroll
            for (int ks = 0; ks < 8; ++ks) {
                bf16x8 af[4];
                #pragma unroll
                for (int ai = 0; ai < 4; ++ai)
                    af[ai] = *(const bf16x8*)(Xb + (16*ai + m16) * LDX + ks*32 + q*8);
                #pragma unroll
                for (int ai = 0; ai < 4; ++ai)
                    #pragma unroll
                    for (int bj = 0; bj < 4; ++bj)
                        hacc[ai][bj] = __builtin_amdgcn_mfma_f32_16x16x32_bf16(af[ai], wb[ks % 3][bj], hacc[ai][bj], 0, 0, 0);
                if (ks < 5) {
                    #pragma unroll
                    for (int bj = 0; bj < 4; ++bj)
                        wb[ks % 3][bj] = *(const bf16x8*)(w1c + bj * 4096 + (ks + 3) * 512);
                }
            }
            // preload stage-2(nc) ks=0..2 (overlaps gelu + barrier)
            #pragma unroll
            for (int k = 0; k < 3; ++k)
                #pragma unroll
                for (int bj = 0; bj < 4; ++bj)
                    wb[k][bj] = *(const bf16x8*)(w2c + bj * 16384 + k * 512);

            #pragma unroll
            for (int bj = 0; bj < 4; ++bj) {
                int colc = 64*w + 16*bj + m16;
                float bv = b1[e * HDIM + nc * 256 + colc];
                #pragma unroll
                for (int ai = 0; ai < 4; ++ai)
                    #pragma unroll
                    for (int r = 0; r < 4; ++r) {
                        int row = 16*ai + 4*q + r;
                        Hb[row * LDX + colc] = f2bf(gelu_fast(hacc[ai][bj][r] + bv));
                    }
            }
            __syncthreads();   // Hb visible

            // ---- stage 2: acc += Hc @ W2[nc] ----
            #pragma unroll
            for (int ks = 0; ks < 8; ++ks) {
                bf16x8 af[4];
                #pragma unroll
                for (int ai = 0; ai < 4; ++ai)
                    af[ai] = *(const bf16x8*)(Hb + (16*ai + m16) * LDX + ks*32 + q*8);
                #pragma unroll
                for (int ai = 0; ai < 4; ++ai)
                    #pragma unroll
                    for (int bj = 0; bj < 4; ++bj)
                        acc[ai][bj] = __builtin_amdgcn_mfma_f32_16x16x32_bf16(af[ai], wb[ks % 3][bj], acc[ai][bj], 0, 0, 0);
                if (ks < 5) {
                    #pragma unroll
                    for (int bj = 0; bj < 4; ++bj)
                        wb[ks % 3][bj] = *(const bf16x8*)(w2c + bj * 16384 + (ks + 3) * 512);
                }
            }
            if (hc == 0) {
                // preload stage-1(nc0+1) ks=0..2 (overlaps closing barrier)
                const unsigned short* w1x = W1s + ((size_t)(e * 64 + (nc0 + 1) * 16 + 4 * w) * 8) * 512 + l * 8;
                #pragma unroll
                for (int k = 0; k < 3; ++k)
                    #pragma unroll
                    for (int bj = 0; bj < 4; ++bj)
                        wb[k][bj] = *(const bf16x8*)(w1x + bj * 4096 + k * 512);
            }
            __syncthreads();   // Hb consumed, safe to overwrite next hc
        }

        // scratch write: weighted contribution, b2 folded into c2==0 half
        #pragma unroll
        for (int bj = 0; bj < 4; ++bj) {
            int col = 64*w + 16*bj + m16;
            float b2v = (c2 == 0) ? b2[e * CDIM + col] : 0.f;
            #pragma unroll
            for (int ai = 0; ai < 4; ++ai)
                #pragma unroll
                for (int r = 0; r < 4; ++r) {
                    int row = 16*ai + 4*q + r;
                    float v = (acc[ai][bj][r] + b2v) * wgts[row];
                    scratch[((size_t)c2 * SROWS + srow[row]) * 256 + col] = v;
                }
        }
    }
}

// =============== reduce: out[n][c] = sum over 4 slots x 2 halves ===============
__global__ void k_reduce(const float* __restrict__ scratch, float* __restrict__ out)
{
    const int gid = blockIdx.x * 256 + threadIdx.x;   // 262144 = 4096 tokens * 64 float4
    const int n = gid >> 6, c4 = (gid & 63) * 4;
    const float* s0 = scratch + ((size_t)n * 4) * 256 + c4;
    const float* s1 = scratch + ((size_t)SROWS + (size_t)n * 4) * 256 + c4;
    f32x4 acc = *(const f32x4*)(s0);
    acc += *(const f32x4*)(s0 + 256);
    acc += *(const f32x4*)(s0 + 512);
    acc += *(const f32x4*)(s0 + 768);
    acc += *(const f32x4*)(s1);
    acc += *(const f32x4*)(s1 + 256);
    acc += *(const f32x4*)(s1 + 512);
    acc += *(const f32x4*)(s1 + 768);
    *(f32x4*)(out + (size_t)n * CDIM + c4) = acc;
}

extern "C" void kernel_launch(void* const* d_in, const int* in_sizes, int n_in,
                              void* d_out, int out_size, void* d_ws, size_t ws_size,
                              hipStream_t stream)
{
    const float* x  = (const float*)d_in[0];
    const float* gW = (const float*)d_in[1];
    const float* gb = (const float*)d_in[2];
    const float* eb = (const float*)d_in[3];
    const float* W1 = (const float*)d_in[4];
    const float* b1 = (const float*)d_in[5];
    const float* W2 = (const float*)d_in[6];
    const float* b2 = (const float*)d_in[7];
    float* out = (float*)d_out;
    float* rw  = out + (size_t)NTOK * CDIM;   // second output: router_weights [N, 32]

    char* p = (char*)d_ws;
    int*   cnt8 = (int*)p;                           // 31*8 line-padded counters (32 KB)
    float* w4   = (float*)(p + 32768);               // 16384 floats
    int*   list = (int*)(p + 32768 + 65536);         // 32*4096 ints (sharded buckets)
    unsigned short* xbuf = (unsigned short*)(p + (1 << 20));   // 2 MB
    unsigned short* W1s  = xbuf + (size_t)NTOK * CDIM;         // 16.78 MB
    unsigned short* W2s  = W1s + (size_t)NEXP * CDIM * HDIM;   // 16.78 MB
    float* scratch = (float*)(p + ((size_t)40 << 20));         // 2*16385*256*4 = 33.6 MB

    hipMemsetAsync(cnt8, 0, 32768, stream);   // sharded expert counters

    k_prep<<<3072, 256, 0, stream>>>(x, gW, gb, eb, W1, W2,
                                     rw, xbuf, cnt8, list, w4, W1s, W2s);
    k_moe<<<512, 256, 0, stream>>>(xbuf, W1s, b1, W2s, b2, cnt8, list, w4, scratch);
    k_reduce<<<1024, 256, 0, stream>>>(scratch, out);
}